// Round 12
// baseline (171.852 us; speedup 1.0000x reference)
//
#include <hip/hip_runtime.h>
#include <math.h>

#define NV 720
#define NU 736
#define NXY 512

// ---------------- Stage 1+2: cosine weight + Ram-Lak Toeplitz GEMM (+ trig table) ------
__global__ __launch_bounds__(192) void filter_kernel(const float* __restrict__ sino,
                                                     float* __restrict__ Q,
                                                     float4* __restrict__ trig) {
    __shared__ float s4[2][368][4];   // [parity][m][view]
    __shared__ float wco[736];        // wco[i] = -1/(pi*(2i-735)*DU)^2
    const int v0 = blockIdx.x * 4;
    const int t = threadIdx.x;

    if (t < 4) {
        int v = v0 + t;
        float beta = (float)((double)v * (2.0 * M_PI / 720.0));
        float cb = cosf(beta), sb = sinf(beta);
        const float K = (float)(1085.6 / 1.2858);   // DSD/DU
        trig[v] = make_float4(cb * K, sb * K, cb, sb);
    }
    for (int i = t; i < 736; i += 192) {
        double n = (double)(2 * i - 735);
        double a = M_PI * n * 1.2858;
        wco[i] = (float)(-1.0 / (a * a));
    }
    const float DSD2 = (float)(1085.6 * 1085.6);
    for (int vv = 0; vv < 4; ++vv) {
        for (int u = t; u < 736; u += 192) {
            float us = ((float)u - 367.5f) * 1.2858f;
            float cw = 1085.6f / sqrtf(DSD2 + us * us);
            s4[u & 1][u >> 1][vv] = sino[(v0 + vv) * NU + u] * cw;
        }
    }
    __syncthreads();

    if (t < 184) {
        const int pj = (t < 92) ? 1 : 0;
        const int J0 = (t < 92) ? t : t - 92;
        const int q = 1 - pj;
        float acc[4][4];
        #pragma unroll
        for (int r = 0; r < 4; ++r)
            #pragma unroll
            for (int vv = 0; vv < 4; ++vv) acc[r][vv] = 0.0f;

        const int ibase0 = J0 + 367 + pj;
        #pragma unroll 4
        for (int m = 0; m < 368; ++m) {
            const float4 sv = *(const float4*)&s4[q][m][0];
            const int ib = ibase0 - m;
            const float w0 = wco[ib];
            const float w1 = wco[ib + 92];
            const float w2 = wco[ib + 184];
            const float w3 = wco[ib + 276];
            acc[0][0] = fmaf(w0, sv.x, acc[0][0]);
            acc[0][1] = fmaf(w0, sv.y, acc[0][1]);
            acc[0][2] = fmaf(w0, sv.z, acc[0][2]);
            acc[0][3] = fmaf(w0, sv.w, acc[0][3]);
            acc[1][0] = fmaf(w1, sv.x, acc[1][0]);
            acc[1][1] = fmaf(w1, sv.y, acc[1][1]);
            acc[1][2] = fmaf(w1, sv.z, acc[1][2]);
            acc[1][3] = fmaf(w1, sv.w, acc[1][3]);
            acc[2][0] = fmaf(w2, sv.x, acc[2][0]);
            acc[2][1] = fmaf(w2, sv.y, acc[2][1]);
            acc[2][2] = fmaf(w2, sv.z, acc[2][2]);
            acc[2][3] = fmaf(w2, sv.w, acc[2][3]);
            acc[3][0] = fmaf(w3, sv.x, acc[3][0]);
            acc[3][1] = fmaf(w3, sv.y, acc[3][1]);
            acc[3][2] = fmaf(w3, sv.z, acc[3][2]);
            acc[3][3] = fmaf(w3, sv.w, acc[3][3]);
        }
        const float H0 = (float)(1.0 / (4.0 * 1.2858 * 1.2858));
        #pragma unroll
        for (int r = 0; r < 4; ++r) {
            const float4 c = *(const float4*)&s4[pj][J0 + 92 * r][0];
            acc[r][0] = fmaf(H0, c.x, acc[r][0]);
            acc[r][1] = fmaf(H0, c.y, acc[r][1]);
            acc[r][2] = fmaf(H0, c.z, acc[r][2]);
            acc[r][3] = fmaf(H0, c.w, acc[r][3]);
        }
        #pragma unroll
        for (int r = 0; r < 4; ++r) {
            const int j = 2 * (J0 + 92 * r) + pj;
            #pragma unroll
            for (int vv = 0; vv < 4; ++vv)
                Q[(v0 + vv) * NU + j] = acc[r][vv] * 1.2858f;
        }
    }
}

// ---------------- Stage 3: backprojection — symmetry + coalesced fetch EVERYWHERE ------
// R11 analysis: interior waves are DS-crossbar-bound (~38us: 32 bpermute/iter, per-CU
// LDS unit ~4cyc each; VALUBusy 45% = VALU 18us / DS 38us). Wall 77us = exterior
// straggler tail (360 divergent loads/wave — R9 proved divergence resolution is the
// invariant cost). THIS ROUND: exterior waves also fetch via coalesced window +
// bpermute. Gate region {0<=fidx<=735} is convex (u=Kc*t/D, D>0 -> two half-planes);
// over gate-cap-tile |grad fidx| <= (Kc/D)(1+|t|/D) <= 2.70*1.435 = 3.87 bins/mm
// x 7.73mm tile diag <= 30 bins -> all IN-GATE lanes fit a 64-bin window based at
// (first in-gate lane's i0c - 32, clamped to [0,672]). Out-gate lanes read wrapped
// finite garbage x g=0. Gate/clamp/fract chains stay R3-BIT-EXACT (R4 lesson);
// fetched elements for contributing lanes identical -> absmax unchanged.
// Interior path: unchanged from R10/R11 (passed twice).
__global__ __launch_bounds__(256) void bp_kernel(const float* __restrict__ Q,
                                                 const float4* __restrict__ trig,
                                                 float* __restrict__ out) {
    const int b = blockIdx.x;
    const int c = b & 7;                      // view chunk (stride-8 partition)
    const int blk = b >> 3;                   // 256 quadrant blocks of 16x16
    const int bx = blk >> 4;
    const int by = blk & 15;
    const int t = threadIdx.x;
    const int w = t >> 6;
    const int l = t & 63;
    const int iq = (bx << 4) + ((w >> 1) << 3) + (l >> 3);   // [0,256)
    const int jq = (by << 4) + ((w & 1) << 3) + (l & 7);     // [0,256)

    const float dx = 400.0f / 512.0f;         // 0.78125 exact
    const float X = ((float)iq - 255.5f) * dx;   // < 0
    const float Y = ((float)jq - 255.5f) * dx;   // < 0
    const float Kc = (float)(1085.6 / 1.2858);

    float acc0 = 0.0f, acc1 = 0.0f, acc2 = 0.0f, acc3 = 0.0f;
    const bool inr = fmaf(X, X, Y * Y) <= 236.5f * 236.5f;

    if (__all(inr)) {
        // ---- interior: base views {c, c+8, ...} in [0,180); rows v, v+180, v+360, v+540
        const int nk = (c < 4) ? 23 : 22;     // ceil((180-c)/8)
        const float* qv0 = Q + c * NU;
        const float* qv1 = qv0 + 180 * NU;
        const float* qv2 = qv0 + 360 * NU;
        const float* qv3 = qv0 + 540 * NU;
        const float4* tvp = trig + c;
        for (int it = 0; it < nk; ++it) {
            const float4 tv = *tvp;                       // cb = tv.z, sb = tv.w
            float a = fmaf(tv.z, X, tv.w * Y);            // t0
            float bb = fmaf(tv.z, Y, -tv.w * X);          // s0
            float aK = a * Kc, bK = bb * Kc;
            float D0 = 595.0f - bb, D1 = 595.0f + a, D2 = 595.0f + bb, D3 = 595.0f - a;
            float r0 = __builtin_amdgcn_rcpf(D0);
            float r1 = __builtin_amdgcn_rcpf(D1);
            float r2 = __builtin_amdgcn_rcpf(D2);
            float r3 = __builtin_amdgcn_rcpf(D3);
            float fi0 = fmaf(aK,  r0, 367.5f);
            float fi1 = fmaf(bK,  r1, 367.5f);
            float fi2 = fmaf(-aK, r2, 367.5f);
            float fi3 = fmaf(-bK, r3, 367.5f);
            int i0 = (int)fi0, i1 = (int)fi1, i2 = (int)fi2, i3 = (int)fi3;
            float f0 = __builtin_amdgcn_fractf(fi0);
            float f1 = __builtin_amdgcn_fractf(fi1);
            float f2 = __builtin_amdgcn_fractf(fi2);
            float f3 = __builtin_amdgcn_fractf(fi3);
            int b0 = min(max(__builtin_amdgcn_readfirstlane(i0) - 32, 0), NU - 64);
            int b1 = min(max(__builtin_amdgcn_readfirstlane(i1) - 32, 0), NU - 64);
            int b2 = min(max(__builtin_amdgcn_readfirstlane(i2) - 32, 0), NU - 64);
            int b3 = min(max(__builtin_amdgcn_readfirstlane(i3) - 32, 0), NU - 64);
            int base[4] = {b0, b1, b2, b3};
            int rel4[4] = {(i0 - b0) << 2, (i1 - b1) << 2, (i2 - b2) << 2, (i3 - b3) << 2};
            float ff[4] = {f0, f1, f2, f3};
            float gg[4] = {r0 * r0, r1 * r1, r2 * r2, r3 * r3};
            float qw[4][4];
            #pragma unroll
            for (int m = 0; m < 4; ++m) {
                int off = base[m] + l;                    // uniform base + lane
                qw[m][0] = qv0[off];                      // coalesced dword loads
                qw[m][1] = qv1[off];
                qw[m][2] = qv2[off];
                qw[m][3] = qv3[off];
            }
            float* accp[4] = {&acc0, &acc1, &acc2, &acc3};
            #pragma unroll
            for (int m = 0; m < 4; ++m) {
                #pragma unroll
                for (int k = 0; k < 4; ++k) {
                    float q0 = __hip_ds_bpermutef(rel4[m], qw[m][k]);
                    float q1 = __hip_ds_bpermutef(rel4[m] + 4, qw[m][k]);
                    float val = fmaf(ff[m], q1 - q0, q0);
                    *accp[(m - k) & 3] = fmaf(gg[m], val, *accp[(m - k) & 3]);
                }
            }
            qv0 += 8 * NU; qv1 += 8 * NU; qv2 += 8 * NU; qv3 += 8 * NU;
            tvp += 8;
        }
    } else {
        // ---- exterior: R3-exact chains/gates; coalesced-window fetch (no divergence) --
        const float pX[4] = {X, Y, -X, -Y};
        const float pY[4] = {Y, -X, -Y, X};
        float* accp[4] = {&acc0, &acc1, &acc2, &acc3};
        const float* qr = Q + c * NU;
        const float4* tvp = trig + c;
        for (int u = 0; u < 90; ++u) {
            const float4 tv = *tvp;
            #pragma unroll
            for (int m = 0; m < 4; ++m) {
                float Xm = pX[m], Ym = pY[m];
                float t2 = fmaf(tv.x, Xm, tv.y * Ym);               // R3-exact
                float D  = fmaf(tv.w, Xm, fmaf(tv.z, -Ym, 595.0f)); // R3-exact
                float rD = __builtin_amdgcn_rcpf(D);
                float fidx = fmaf(t2, rD, 367.5f);
                float cen = fidx - 367.5f;                          // R3-exact gate
                bool ing = (__builtin_fabsf(cen) <= 367.5f);
                unsigned long long gm = __ballot(ing);
                if (gm != 0ull) {
                    float g = ing ? rD * rD : 0.0f;
                    int i0c = min(max((int)fidx, 0), NU - 2);       // v_med3_i32
                    float f = __builtin_amdgcn_fractf(fidx);
                    int sl = (int)__builtin_ctzll(gm);              // uniform lane id
                    int ibase = __builtin_amdgcn_readlane(i0c, sl); // in-gate anchor
                    int base = min(max(ibase - 32, 0), NU - 64);
                    float qw = qr[base + l];                        // COALESCED load
                    int rel = (i0c - base) << 2;                    // wraps for g=0 lanes
                    float q0 = __hip_ds_bpermutef(rel, qw);
                    float q1 = __hip_ds_bpermutef(rel + 4, qw);
                    float val = fmaf(f, q1 - q0, q0);
                    *accp[m] = fmaf(g, val, *accp[m]);
                }
            }
            qr += 8 * NU;
            tvp += 8;
        }
    }
    const float SC = (float)(595.0 * 595.0 * 0.5 * (2.0 * M_PI / 720.0));
    const int ir = 511 - iq, jr = 511 - jq;
    unsafeAtomicAdd(&out[iq * NXY + jq], acc0 * SC);   // P0 = (iq, jq)
    unsafeAtomicAdd(&out[jq * NXY + ir], acc1 * SC);   // P1 = (jq, 511-iq)
    unsafeAtomicAdd(&out[ir * NXY + jr], acc2 * SC);   // P2 = (511-iq, 511-jq)
    unsafeAtomicAdd(&out[jr * NXY + iq], acc3 * SC);   // P3 = (511-jq, iq)
}

extern "C" void kernel_launch(void* const* d_in, const int* in_sizes, int n_in,
                              void* d_out, int out_size, void* d_ws, size_t ws_size,
                              hipStream_t stream) {
    const float* sino = (const float*)d_in[0];
    float* out = (float*)d_out;
    float* Q = (float*)d_ws;                                          // 720*736*4 = 2.12 MB
    float4* trig = (float4*)((char*)d_ws + NV * NU * sizeof(float));  // +11.5 KB (16B aligned)

    filter_kernel<<<NV / 4, 192, 0, stream>>>(sino, Q, trig);
    hipMemsetAsync(out, 0, (size_t)NXY * NXY * sizeof(float), stream);  // atomic targets
    bp_kernel<<<2048, 256, 0, stream>>>(Q, trig, out);
}

// Round 13
// 137.942 us; speedup vs baseline: 1.2458x; 1.2458x over previous
//
#include <hip/hip_runtime.h>
#include <math.h>

#define NV 720
#define NU 736
#define NXY 512

// ---------------- Stage 1+2: cosine weight + Ram-Lak Toeplitz GEMM (+ trig, + out=0) ---
__global__ __launch_bounds__(192) void filter_kernel(const float* __restrict__ sino,
                                                     float* __restrict__ Q,
                                                     float4* __restrict__ trig,
                                                     float* __restrict__ out_zero) {
    __shared__ float s4[2][368][4];   // [parity][m][view]
    __shared__ float wco[736];        // wco[i] = -1/(pi*(2i-735)*DU)^2
    const int v0 = blockIdx.x * 4;
    const int t = threadIdx.x;

    // zero the atomic target (replaces the hipMemsetAsync dispatch; bp launches after)
    for (int i = blockIdx.x * 192 + t; i < NXY * NXY; i += 180 * 192)
        out_zero[i] = 0.0f;

    if (t < 4) {
        int v = v0 + t;
        float beta = (float)((double)v * (2.0 * M_PI / 720.0));
        float cb = cosf(beta), sb = sinf(beta);
        const float K = (float)(1085.6 / 1.2858);   // DSD/DU
        trig[v] = make_float4(cb * K, sb * K, cb, sb);
    }
    for (int i = t; i < 736; i += 192) {
        double n = (double)(2 * i - 735);
        double a = M_PI * n * 1.2858;
        wco[i] = (float)(-1.0 / (a * a));
    }
    const float DSD2 = (float)(1085.6 * 1085.6);
    for (int vv = 0; vv < 4; ++vv) {
        for (int u = t; u < 736; u += 192) {
            float us = ((float)u - 367.5f) * 1.2858f;
            float cw = 1085.6f / sqrtf(DSD2 + us * us);
            s4[u & 1][u >> 1][vv] = sino[(v0 + vv) * NU + u] * cw;
        }
    }
    __syncthreads();

    if (t < 184) {
        const int pj = (t < 92) ? 1 : 0;
        const int J0 = (t < 92) ? t : t - 92;
        const int q = 1 - pj;
        float acc[4][4];
        #pragma unroll
        for (int r = 0; r < 4; ++r)
            #pragma unroll
            for (int vv = 0; vv < 4; ++vv) acc[r][vv] = 0.0f;

        const int ibase0 = J0 + 367 + pj;
        #pragma unroll 4
        for (int m = 0; m < 368; ++m) {
            const float4 sv = *(const float4*)&s4[q][m][0];
            const int ib = ibase0 - m;
            const float w0 = wco[ib];
            const float w1 = wco[ib + 92];
            const float w2 = wco[ib + 184];
            const float w3 = wco[ib + 276];
            acc[0][0] = fmaf(w0, sv.x, acc[0][0]);
            acc[0][1] = fmaf(w0, sv.y, acc[0][1]);
            acc[0][2] = fmaf(w0, sv.z, acc[0][2]);
            acc[0][3] = fmaf(w0, sv.w, acc[0][3]);
            acc[1][0] = fmaf(w1, sv.x, acc[1][0]);
            acc[1][1] = fmaf(w1, sv.y, acc[1][1]);
            acc[1][2] = fmaf(w1, sv.z, acc[1][2]);
            acc[1][3] = fmaf(w1, sv.w, acc[1][3]);
            acc[2][0] = fmaf(w2, sv.x, acc[2][0]);
            acc[2][1] = fmaf(w2, sv.y, acc[2][1]);
            acc[2][2] = fmaf(w2, sv.z, acc[2][2]);
            acc[2][3] = fmaf(w2, sv.w, acc[2][3]);
            acc[3][0] = fmaf(w3, sv.x, acc[3][0]);
            acc[3][1] = fmaf(w3, sv.y, acc[3][1]);
            acc[3][2] = fmaf(w3, sv.z, acc[3][2]);
            acc[3][3] = fmaf(w3, sv.w, acc[3][3]);
        }
        const float H0 = (float)(1.0 / (4.0 * 1.2858 * 1.2858));
        #pragma unroll
        for (int r = 0; r < 4; ++r) {
            const float4 c = *(const float4*)&s4[pj][J0 + 92 * r][0];
            acc[r][0] = fmaf(H0, c.x, acc[r][0]);
            acc[r][1] = fmaf(H0, c.y, acc[r][1]);
            acc[r][2] = fmaf(H0, c.z, acc[r][2]);
            acc[r][3] = fmaf(H0, c.w, acc[r][3]);
        }
        #pragma unroll
        for (int r = 0; r < 4; ++r) {
            const int j = 2 * (J0 + 92 * r) + pj;
            #pragma unroll
            for (int vv = 0; vv < 4; ++vv)
                Q[(v0 + vv) * NU + j] = acc[r][vv] * 1.2858f;
        }
    }
}

// ---------------- Stage 3: backprojection — R11 structure, 16-way view split -----------
// R12 lesson: branch-wrapped scalar-anchored fetch serializes load->bpermute chains
// (108us). Reverted to R11's exterior (divergent dwordx2, pipelined). R10->R11 showed
// wall = interior phase (~55-60us) + SOLO straggler tail (last wave per CU). This round
// halves the tail QUANTUM: 16 view chunks -> 4096 blocks, exterior waves 45 iters.
// Per-px-view arithmetic bit-identical to R11 (passed, 3.05e-4); only atomic summation
// order changes (absmax-neutral: R5/R11 precedent).
// Symmetry + window proof: see R10. EXTERIOR: R3-exact chains (R4 lesson). 1 px/lane (R5).
__global__ __launch_bounds__(256) void bp_kernel(const float* __restrict__ Q,
                                                 const float4* __restrict__ trig,
                                                 float* __restrict__ out) {
    const int b = blockIdx.x;
    const int c = b & 15;                     // view chunk (stride-16 partition)
    const int blk = b >> 4;                   // 256 quadrant blocks of 16x16
    const int bx = blk >> 4;
    const int by = blk & 15;
    const int t = threadIdx.x;
    const int w = t >> 6;
    const int l = t & 63;
    const int iq = (bx << 4) + ((w >> 1) << 3) + (l >> 3);   // [0,256)
    const int jq = (by << 4) + ((w & 1) << 3) + (l & 7);     // [0,256)

    const float dx = 400.0f / 512.0f;         // 0.78125 exact
    const float X = ((float)iq - 255.5f) * dx;   // < 0
    const float Y = ((float)jq - 255.5f) * dx;   // < 0
    const float Kc = (float)(1085.6 / 1.2858);

    float acc0 = 0.0f, acc1 = 0.0f, acc2 = 0.0f, acc3 = 0.0f;
    const bool inr = fmaf(X, X, Y * Y) <= 236.5f * 236.5f;

    if (__all(inr)) {
        // ---- interior: base views {c, c+16, ...} in [0,180); rows v,v+180,v+360,v+540
        const int nk = (c < 4) ? 12 : 11;     // ceil((180-c)/16)
        const float* qv0 = Q + c * NU;
        const float* qv1 = qv0 + 180 * NU;
        const float* qv2 = qv0 + 360 * NU;
        const float* qv3 = qv0 + 540 * NU;
        const float4* tvp = trig + c;
        for (int it = 0; it < nk; ++it) {
            const float4 tv = *tvp;                       // cb = tv.z, sb = tv.w
            float a = fmaf(tv.z, X, tv.w * Y);            // t0
            float bb = fmaf(tv.z, Y, -tv.w * X);          // s0
            float aK = a * Kc, bK = bb * Kc;
            float D0 = 595.0f - bb, D1 = 595.0f + a, D2 = 595.0f + bb, D3 = 595.0f - a;
            float r0 = __builtin_amdgcn_rcpf(D0);
            float r1 = __builtin_amdgcn_rcpf(D1);
            float r2 = __builtin_amdgcn_rcpf(D2);
            float r3 = __builtin_amdgcn_rcpf(D3);
            float fi0 = fmaf(aK,  r0, 367.5f);
            float fi1 = fmaf(bK,  r1, 367.5f);
            float fi2 = fmaf(-aK, r2, 367.5f);
            float fi3 = fmaf(-bK, r3, 367.5f);
            int i0 = (int)fi0, i1 = (int)fi1, i2 = (int)fi2, i3 = (int)fi3;
            float f0 = __builtin_amdgcn_fractf(fi0);
            float f1 = __builtin_amdgcn_fractf(fi1);
            float f2 = __builtin_amdgcn_fractf(fi2);
            float f3 = __builtin_amdgcn_fractf(fi3);
            int b0 = min(max(__builtin_amdgcn_readfirstlane(i0) - 32, 0), NU - 64);
            int b1 = min(max(__builtin_amdgcn_readfirstlane(i1) - 32, 0), NU - 64);
            int b2 = min(max(__builtin_amdgcn_readfirstlane(i2) - 32, 0), NU - 64);
            int b3 = min(max(__builtin_amdgcn_readfirstlane(i3) - 32, 0), NU - 64);
            int base[4] = {b0, b1, b2, b3};
            int rel4[4] = {(i0 - b0) << 2, (i1 - b1) << 2, (i2 - b2) << 2, (i3 - b3) << 2};
            float ff[4] = {f0, f1, f2, f3};
            float gg[4] = {r0 * r0, r1 * r1, r2 * r2, r3 * r3};
            float qw[4][4];
            #pragma unroll
            for (int m = 0; m < 4; ++m) {
                int off = base[m] + l;                    // uniform base + lane
                qw[m][0] = qv0[off];                      // coalesced dword loads
                qw[m][1] = qv1[off];
                qw[m][2] = qv2[off];
                qw[m][3] = qv3[off];
            }
            float* accp[4] = {&acc0, &acc1, &acc2, &acc3};
            #pragma unroll
            for (int m = 0; m < 4; ++m) {
                #pragma unroll
                for (int k = 0; k < 4; ++k) {
                    float q0 = __hip_ds_bpermutef(rel4[m], qw[m][k]);
                    float q1 = __hip_ds_bpermutef(rel4[m] + 4, qw[m][k]);
                    float val = fmaf(ff[m], q1 - q0, q0);
                    *accp[(m - k) & 3] = fmaf(gg[m], val, *accp[(m - k) & 3]);
                }
            }
            qv0 += 16 * NU; qv1 += 16 * NU; qv2 += 16 * NU; qv3 += 16 * NU;
            tvp += 16;
        }
    } else {
        // ---- exterior: R7-exact chains; views {c, c+16, ..., c+704} (45 iters) -------
        const float pX[4] = {X, Y, -X, -Y};
        const float pY[4] = {Y, -X, -Y, X};
        float* accp[4] = {&acc0, &acc1, &acc2, &acc3};
        const float* qr = Q + c * NU;
        const float4* tvp = trig + c;
        for (int u = 0; u < 45; ++u) {
            const float4 tv = *tvp;
            #pragma unroll
            for (int m = 0; m < 4; ++m) {
                float Xm = pX[m], Ym = pY[m];
                float t2 = fmaf(tv.x, Xm, tv.y * Ym);               // R3-exact
                float D  = fmaf(tv.w, Xm, fmaf(tv.z, -Ym, 595.0f)); // R3-exact
                float rD = __builtin_amdgcn_rcpf(D);
                float fidx = fmaf(t2, rD, 367.5f);
                int i0 = (int)fidx;
                int i0c = min(max(i0, 0), NU - 2);                  // v_med3_i32
                float f = __builtin_amdgcn_fractf(fidx);
                float2 qq = *(const float2*)(qr + i0c);             // divergent dwordx2
                float val = fmaf(f, qq.y - qq.x, qq.x);
                float g = rD * rD;
                float cen = fidx - 367.5f;
                g = (__builtin_fabsf(cen) <= 367.5f) ? g : 0.0f;
                *accp[m] = fmaf(g, val, *accp[m]);
            }
            qr += 16 * NU;
            tvp += 16;
        }
    }
    const float SC = (float)(595.0 * 595.0 * 0.5 * (2.0 * M_PI / 720.0));
    const int ir = 511 - iq, jr = 511 - jq;
    unsafeAtomicAdd(&out[iq * NXY + jq], acc0 * SC);   // P0 = (iq, jq)
    unsafeAtomicAdd(&out[jq * NXY + ir], acc1 * SC);   // P1 = (jq, 511-iq)
    unsafeAtomicAdd(&out[ir * NXY + jr], acc2 * SC);   // P2 = (511-iq, 511-jq)
    unsafeAtomicAdd(&out[jr * NXY + iq], acc3 * SC);   // P3 = (511-jq, iq)
}

extern "C" void kernel_launch(void* const* d_in, const int* in_sizes, int n_in,
                              void* d_out, int out_size, void* d_ws, size_t ws_size,
                              hipStream_t stream) {
    const float* sino = (const float*)d_in[0];
    float* out = (float*)d_out;
    float* Q = (float*)d_ws;                                          // 720*736*4 = 2.12 MB
    float4* trig = (float4*)((char*)d_ws + NV * NU * sizeof(float));  // +11.5 KB (16B aligned)

    filter_kernel<<<NV / 4, 192, 0, stream>>>(sino, Q, trig, out);    // also zeroes out
    bp_kernel<<<4096, 256, 0, stream>>>(Q, trig, out);
}

// Round 14
// 119.695 us; speedup vs baseline: 1.4358x; 1.1524x over previous
//
#include <hip/hip_runtime.h>
#include <math.h>

#define NV 720
#define NU 736
#define NUP 768      // padded Q row stride (bins 736..767 never gathered)
#define NXY 512

// ---------------- Stage 1+2: cosine weight + Ram-Lak Toeplitz GEMM (+ trig, + out=0) ---
// Q written with padded stride NUP=768 so bp can stage rows with 3x 1KB global_load_lds.
__global__ __launch_bounds__(192) void filter_kernel(const float* __restrict__ sino,
                                                     float* __restrict__ Q,
                                                     float4* __restrict__ trig,
                                                     float* __restrict__ out_zero) {
    __shared__ float s4[2][368][4];   // [parity][m][view]
    __shared__ float wco[736];        // wco[i] = -1/(pi*(2i-735)*DU)^2
    const int v0 = blockIdx.x * 4;
    const int t = threadIdx.x;

    // zero the atomic target (replaces the hipMemsetAsync dispatch; bp launches after)
    for (int i = blockIdx.x * 192 + t; i < NXY * NXY; i += 180 * 192)
        out_zero[i] = 0.0f;

    if (t < 4) {
        int v = v0 + t;
        float beta = (float)((double)v * (2.0 * M_PI / 720.0));
        float cb = cosf(beta), sb = sinf(beta);
        const float K = (float)(1085.6 / 1.2858);   // DSD/DU
        trig[v] = make_float4(cb * K, sb * K, cb, sb);
    }
    for (int i = t; i < 736; i += 192) {
        double n = (double)(2 * i - 735);
        double a = M_PI * n * 1.2858;
        wco[i] = (float)(-1.0 / (a * a));
    }
    const float DSD2 = (float)(1085.6 * 1085.6);
    for (int vv = 0; vv < 4; ++vv) {
        for (int u = t; u < 736; u += 192) {
            float us = ((float)u - 367.5f) * 1.2858f;
            float cw = 1085.6f / sqrtf(DSD2 + us * us);
            s4[u & 1][u >> 1][vv] = sino[(v0 + vv) * NU + u] * cw;
        }
    }
    __syncthreads();

    if (t < 184) {
        const int pj = (t < 92) ? 1 : 0;
        const int J0 = (t < 92) ? t : t - 92;
        const int q = 1 - pj;
        float acc[4][4];
        #pragma unroll
        for (int r = 0; r < 4; ++r)
            #pragma unroll
            for (int vv = 0; vv < 4; ++vv) acc[r][vv] = 0.0f;

        const int ibase0 = J0 + 367 + pj;
        #pragma unroll 4
        for (int m = 0; m < 368; ++m) {
            const float4 sv = *(const float4*)&s4[q][m][0];
            const int ib = ibase0 - m;
            const float w0 = wco[ib];
            const float w1 = wco[ib + 92];
            const float w2 = wco[ib + 184];
            const float w3 = wco[ib + 276];
            acc[0][0] = fmaf(w0, sv.x, acc[0][0]);
            acc[0][1] = fmaf(w0, sv.y, acc[0][1]);
            acc[0][2] = fmaf(w0, sv.z, acc[0][2]);
            acc[0][3] = fmaf(w0, sv.w, acc[0][3]);
            acc[1][0] = fmaf(w1, sv.x, acc[1][0]);
            acc[1][1] = fmaf(w1, sv.y, acc[1][1]);
            acc[1][2] = fmaf(w1, sv.z, acc[1][2]);
            acc[1][3] = fmaf(w1, sv.w, acc[1][3]);
            acc[2][0] = fmaf(w2, sv.x, acc[2][0]);
            acc[2][1] = fmaf(w2, sv.y, acc[2][1]);
            acc[2][2] = fmaf(w2, sv.z, acc[2][2]);
            acc[2][3] = fmaf(w2, sv.w, acc[2][3]);
            acc[3][0] = fmaf(w3, sv.x, acc[3][0]);
            acc[3][1] = fmaf(w3, sv.y, acc[3][1]);
            acc[3][2] = fmaf(w3, sv.z, acc[3][2]);
            acc[3][3] = fmaf(w3, sv.w, acc[3][3]);
        }
        const float H0 = (float)(1.0 / (4.0 * 1.2858 * 1.2858));
        #pragma unroll
        for (int r = 0; r < 4; ++r) {
            const float4 c = *(const float4*)&s4[pj][J0 + 92 * r][0];
            acc[r][0] = fmaf(H0, c.x, acc[r][0]);
            acc[r][1] = fmaf(H0, c.y, acc[r][1]);
            acc[r][2] = fmaf(H0, c.z, acc[r][2]);
            acc[r][3] = fmaf(H0, c.w, acc[r][3]);
        }
        #pragma unroll
        for (int r = 0; r < 4; ++r) {
            const int j = 2 * (J0 + 92 * r) + pj;
            #pragma unroll
            for (int vv = 0; vv < 4; ++vv)
                Q[(v0 + vv) * NUP + j] = acc[r][vv] * 1.2858f;
        }
    }
}

// ---------------- Stage 3: backprojection — LDS-staged rows, ds_read2 gathers ----------
// R13 finding: wall 77us == DS-crossbar saturation: 8.2M bpermutes x ~5.8cyc / 256 CUs.
// THIS ROUND: per iter, the block stages its 4 Q rows (view v, v+180, v+360, v+540;
// 12KB) into LDS via global_load_lds (wave w stages row w, 3 x 16B-wide issues), then
// every bilinear gather is ONE ds_read2_b32 (both taps; conflict-free: wave bin-spread
// <=40 < 32-bank wrap means only same-address broadcast + free 2-way). DS ops/iter
// 48 -> ~19. Full rows kill the window-base machinery AND let exterior waves use the
// same staged fetch with their R3-BIT-EXACT chains (i0c in [0,734] always valid).
// Values fetched bit-identical; per-pixel view partition is a re-partition under
// atomics (absmax-neutral precedent R5/R11/R13).
// Lessons kept: no reassociation of gate chains (R4); 1 px/lane (R5); no per-view
// branches around fetches (R12).
__global__ __launch_bounds__(256) void bp_kernel(const float* __restrict__ Q,
                                                 const float4* __restrict__ trig,
                                                 float* __restrict__ out) {
    __shared__ float win[4][NUP];             // 12 KB: rows v, v+180, v+360, v+540
    const int b = blockIdx.x;
    const int c = b & 15;                     // view chunk: base views {c, c+16, ...}
    const int blk = b >> 4;                   // 256 quadrant blocks of 16x16
    const int bx = blk >> 4;
    const int by = blk & 15;
    const int t = threadIdx.x;
    const int w = t >> 6;
    const int l = t & 63;
    const int iq = (bx << 4) + ((w >> 1) << 3) + (l >> 3);   // [0,256)
    const int jq = (by << 4) + ((w & 1) << 3) + (l & 7);     // [0,256)

    const float dx = 400.0f / 512.0f;         // 0.78125 exact
    const float X = ((float)iq - 255.5f) * dx;   // < 0
    const float Y = ((float)jq - 255.5f) * dx;   // < 0
    const float Kc = (float)(1085.6 / 1.2858);

    float acc0 = 0.0f, acc1 = 0.0f, acc2 = 0.0f, acc3 = 0.0f;
    const bool inr = fmaf(X, X, Y * Y) <= 236.5f * 236.5f;
    const bool myint = __all(inr);

    const int nk = (c < 4) ? 12 : 11;         // ceil((180-c)/16)
    const float* rowp = Q + (size_t)(c + 180 * w) * NUP;   // wave w stages row w
    const float4* tvp = trig + c;
    const float* winf = &win[0][0];

    for (int it = 0; it < nk; ++it) {
        // ---- stage this iter's 4 rows: wave w -> win[w], 3 x (64 lanes x 16B) --------
        #pragma unroll
        for (int ch = 0; ch < 3; ++ch)
            __builtin_amdgcn_global_load_lds(
                (const __attribute__((address_space(1))) void*)(rowp + ch * 256 + l * 4),
                (__attribute__((address_space(3))) void*)&win[w][ch * 256],
                16, 0, 0);
        __syncthreads();

        if (myint) {
            // ---- interior: symmetric geometry (R10-proven), ds_read2 gathers ---------
            const float4 tv = tvp[0];                     // cb = tv.z, sb = tv.w
            float a = fmaf(tv.z, X, tv.w * Y);            // t0
            float bb = fmaf(tv.z, Y, -tv.w * X);          // s0
            float aK = a * Kc, bK = bb * Kc;
            float D0 = 595.0f - bb, D1 = 595.0f + a, D2 = 595.0f + bb, D3 = 595.0f - a;
            float r0 = __builtin_amdgcn_rcpf(D0);
            float r1 = __builtin_amdgcn_rcpf(D1);
            float r2 = __builtin_amdgcn_rcpf(D2);
            float r3 = __builtin_amdgcn_rcpf(D3);
            float fi0 = fmaf(aK,  r0, 367.5f);
            float fi1 = fmaf(bK,  r1, 367.5f);
            float fi2 = fmaf(-aK, r2, 367.5f);
            float fi3 = fmaf(-bK, r3, 367.5f);
            int im[4] = {(int)fi0, (int)fi1, (int)fi2, (int)fi3};  // in [1,733]
            float ff[4] = {__builtin_amdgcn_fractf(fi0), __builtin_amdgcn_fractf(fi1),
                           __builtin_amdgcn_fractf(fi2), __builtin_amdgcn_fractf(fi3)};
            float gg[4] = {r0 * r0, r1 * r1, r2 * r2, r3 * r3};
            float* accp[4] = {&acc0, &acc1, &acc2, &acc3};
            #pragma unroll
            for (int m = 0; m < 4; ++m) {
                #pragma unroll
                for (int k = 0; k < 4; ++k) {
                    const float* p = winf + (k * NUP + im[m]);
                    float q0 = p[0];                      // ds_read2_b32 (fused pair)
                    float q1 = p[1];
                    float val = fmaf(ff[m], q1 - q0, q0);
                    *accp[(m - k) & 3] = fmaf(gg[m], val, *accp[(m - k) & 3]);
                }
            }
        } else {
            // ---- exterior: R3-exact chains/gates per pixel, staged ds_read2 fetch ----
            const float4 tvs0 = tvp[0];
            const float4 tvs1 = tvp[180];
            const float4 tvs2 = tvp[360];
            const float4 tvs3 = tvp[540];
            const float4 tvs[4] = {tvs0, tvs1, tvs2, tvs3};
            const float pX[4] = {X, Y, -X, -Y};
            const float pY[4] = {Y, -X, -Y, X};
            float* accp[4] = {&acc0, &acc1, &acc2, &acc3};
            #pragma unroll
            for (int j = 0; j < 4; ++j) {
                float Xm = pX[j], Ym = pY[j];
                #pragma unroll
                for (int k = 0; k < 4; ++k) {
                    const float4 tv = tvs[k];
                    float t2 = fmaf(tv.x, Xm, tv.y * Ym);               // R3-exact
                    float D  = fmaf(tv.w, Xm, fmaf(tv.z, -Ym, 595.0f)); // R3-exact
                    float rD = __builtin_amdgcn_rcpf(D);
                    float fidx = fmaf(t2, rD, 367.5f);
                    int i0c = min(max((int)fidx, 0), NU - 2);           // v_med3_i32
                    float f = __builtin_amdgcn_fractf(fidx);
                    const float* p = winf + (k * NUP + i0c);
                    float q0 = p[0];                                    // ds_read2_b32
                    float q1 = p[1];
                    float val = fmaf(f, q1 - q0, q0);
                    float cen = fidx - 367.5f;                          // R3-exact gate
                    float g = (__builtin_fabsf(cen) <= 367.5f) ? rD * rD : 0.0f;
                    *accp[j] = fmaf(g, val, *accp[j]);
                }
            }
        }
        __syncthreads();
        rowp += 16 * NUP;
        tvp += 16;
    }
    const float SC = (float)(595.0 * 595.0 * 0.5 * (2.0 * M_PI / 720.0));
    const int ir = 511 - iq, jr = 511 - jq;
    unsafeAtomicAdd(&out[iq * NXY + jq], acc0 * SC);   // P0 = (iq, jq)
    unsafeAtomicAdd(&out[jq * NXY + ir], acc1 * SC);   // P1 = (jq, 511-iq)
    unsafeAtomicAdd(&out[ir * NXY + jr], acc2 * SC);   // P2 = (511-iq, 511-jq)
    unsafeAtomicAdd(&out[jr * NXY + iq], acc3 * SC);   // P3 = (511-jq, iq)
}

extern "C" void kernel_launch(void* const* d_in, const int* in_sizes, int n_in,
                              void* d_out, int out_size, void* d_ws, size_t ws_size,
                              hipStream_t stream) {
    const float* sino = (const float*)d_in[0];
    float* out = (float*)d_out;
    float* Q = (float*)d_ws;                                           // 720*768*4 = 2.21 MB
    float4* trig = (float4*)((char*)d_ws + (size_t)NV * NUP * sizeof(float)); // 16B-aligned

    filter_kernel<<<NV / 4, 192, 0, stream>>>(sino, Q, trig, out);     // also zeroes out
    bp_kernel<<<4096, 256, 0, stream>>>(Q, trig, out);
}

// Round 15
// 118.592 us; speedup vs baseline: 1.4491x; 1.0093x over previous
//
#include <hip/hip_runtime.h>
#include <math.h>

#define NV 720
#define NU 736
#define NUP 768      // padded Q row stride (bins 736..767 never gathered)
#define NXY 512

// ---------------- Stage 1+2: cosine weight + Ram-Lak Toeplitz GEMM (+ trig, + out=0) ---
// Q written with padded stride NUP=768 so bp can stage rows with 3x 1KB global_load_lds.
__global__ __launch_bounds__(192) void filter_kernel(const float* __restrict__ sino,
                                                     float* __restrict__ Q,
                                                     float4* __restrict__ trig,
                                                     float* __restrict__ out_zero) {
    __shared__ float s4[2][368][4];   // [parity][m][view]
    __shared__ float wco[736];        // wco[i] = -1/(pi*(2i-735)*DU)^2
    const int v0 = blockIdx.x * 4;
    const int t = threadIdx.x;

    // zero the atomic target (replaces the hipMemsetAsync dispatch; bp launches after)
    for (int i = blockIdx.x * 192 + t; i < NXY * NXY; i += 180 * 192)
        out_zero[i] = 0.0f;

    if (t < 4) {
        int v = v0 + t;
        float beta = (float)((double)v * (2.0 * M_PI / 720.0));
        float cb = cosf(beta), sb = sinf(beta);
        const float K = (float)(1085.6 / 1.2858);   // DSD/DU
        trig[v] = make_float4(cb * K, sb * K, cb, sb);
    }
    for (int i = t; i < 736; i += 192) {
        double n = (double)(2 * i - 735);
        double a = M_PI * n * 1.2858;
        wco[i] = (float)(-1.0 / (a * a));
    }
    const float DSD2 = (float)(1085.6 * 1085.6);
    for (int vv = 0; vv < 4; ++vv) {
        for (int u = t; u < 736; u += 192) {
            float us = ((float)u - 367.5f) * 1.2858f;
            float cw = 1085.6f / sqrtf(DSD2 + us * us);
            s4[u & 1][u >> 1][vv] = sino[(v0 + vv) * NU + u] * cw;
        }
    }
    __syncthreads();

    if (t < 184) {
        const int pj = (t < 92) ? 1 : 0;
        const int J0 = (t < 92) ? t : t - 92;
        const int q = 1 - pj;
        float acc[4][4];
        #pragma unroll
        for (int r = 0; r < 4; ++r)
            #pragma unroll
            for (int vv = 0; vv < 4; ++vv) acc[r][vv] = 0.0f;

        const int ibase0 = J0 + 367 + pj;
        #pragma unroll 4
        for (int m = 0; m < 368; ++m) {
            const float4 sv = *(const float4*)&s4[q][m][0];
            const int ib = ibase0 - m;
            const float w0 = wco[ib];
            const float w1 = wco[ib + 92];
            const float w2 = wco[ib + 184];
            const float w3 = wco[ib + 276];
            acc[0][0] = fmaf(w0, sv.x, acc[0][0]);
            acc[0][1] = fmaf(w0, sv.y, acc[0][1]);
            acc[0][2] = fmaf(w0, sv.z, acc[0][2]);
            acc[0][3] = fmaf(w0, sv.w, acc[0][3]);
            acc[1][0] = fmaf(w1, sv.x, acc[1][0]);
            acc[1][1] = fmaf(w1, sv.y, acc[1][1]);
            acc[1][2] = fmaf(w1, sv.z, acc[1][2]);
            acc[1][3] = fmaf(w1, sv.w, acc[1][3]);
            acc[2][0] = fmaf(w2, sv.x, acc[2][0]);
            acc[2][1] = fmaf(w2, sv.y, acc[2][1]);
            acc[2][2] = fmaf(w2, sv.z, acc[2][2]);
            acc[2][3] = fmaf(w2, sv.w, acc[2][3]);
            acc[3][0] = fmaf(w3, sv.x, acc[3][0]);
            acc[3][1] = fmaf(w3, sv.y, acc[3][1]);
            acc[3][2] = fmaf(w3, sv.z, acc[3][2]);
            acc[3][3] = fmaf(w3, sv.w, acc[3][3]);
        }
        const float H0 = (float)(1.0 / (4.0 * 1.2858 * 1.2858));
        #pragma unroll
        for (int r = 0; r < 4; ++r) {
            const float4 c = *(const float4*)&s4[pj][J0 + 92 * r][0];
            acc[r][0] = fmaf(H0, c.x, acc[r][0]);
            acc[r][1] = fmaf(H0, c.y, acc[r][1]);
            acc[r][2] = fmaf(H0, c.z, acc[r][2]);
            acc[r][3] = fmaf(H0, c.w, acc[r][3]);
        }
        #pragma unroll
        for (int r = 0; r < 4; ++r) {
            const int j = 2 * (J0 + 92 * r) + pj;
            #pragma unroll
            for (int vv = 0; vv < 4; ++vv)
                Q[(v0 + vv) * NUP + j] = acc[r][vv] * 1.2858f;
        }
    }
}

// ---------------- Stage 3: backprojection — LDS-staged rows, DOUBLE-BUFFERED -----------
// R14 confirmed DS-crossbar floor (~29us) + ~20us barrier-drain stall (2 barriers/iter,
// each draining global_load_lds vmcnt(0)). THIS ROUND: double-buffer win[2][4][NUP]
// (24KB): one barrier/iter; next iter's rows are issued right after the barrier and
// have a full compute phase (~1500cyc >> L2-hit ~200cyc) to land -> drain is stall-free.
// Buffer reuse race-free: iter it reads buf[c] before the it+1 barrier; iter it+1
// writes buf[c] after it. ALL arithmetic/fetched values/summation order BIT-IDENTICAL
// to R14 (passed, 3.051758e-04).
// Lessons kept: no gate-chain reassociation (R4); 1 px/lane (R5); no per-view branches
// around fetches (R12); gathers via ds_read2 not bpermute (R14).
__global__ __launch_bounds__(256) void bp_kernel(const float* __restrict__ Q,
                                                 const float4* __restrict__ trig,
                                                 float* __restrict__ out) {
    __shared__ float win[2][4][NUP];          // 24 KB double buffer
    const int b = blockIdx.x;
    const int c = b & 15;                     // view chunk: base views {c, c+16, ...}
    const int blk = b >> 4;                   // 256 quadrant blocks of 16x16
    const int bx = blk >> 4;
    const int by = blk & 15;
    const int t = threadIdx.x;
    const int w = t >> 6;
    const int l = t & 63;
    const int iq = (bx << 4) + ((w >> 1) << 3) + (l >> 3);   // [0,256)
    const int jq = (by << 4) + ((w & 1) << 3) + (l & 7);     // [0,256)

    const float dx = 400.0f / 512.0f;         // 0.78125 exact
    const float X = ((float)iq - 255.5f) * dx;   // < 0
    const float Y = ((float)jq - 255.5f) * dx;   // < 0
    const float Kc = (float)(1085.6 / 1.2858);

    float acc0 = 0.0f, acc1 = 0.0f, acc2 = 0.0f, acc3 = 0.0f;
    const bool inr = fmaf(X, X, Y * Y) <= 236.5f * 236.5f;
    const bool myint = __all(inr);

    const int nk = (c < 4) ? 12 : 11;         // ceil((180-c)/16)
    const float* rowp = Q + (size_t)(c + 180 * w) * NUP;   // wave w stages row w
    const float4* tvp = trig + c;

    // preload iter 0 into buffer 0
    #pragma unroll
    for (int ch = 0; ch < 3; ++ch)
        __builtin_amdgcn_global_load_lds(
            (const __attribute__((address_space(1))) void*)(rowp + ch * 256 + l * 4),
            (__attribute__((address_space(3))) void*)&win[0][w][ch * 256],
            16, 0, 0);

    for (int it = 0; it < nk; ++it) {
        __syncthreads();                      // win[it&1] staged; prior reads of it^1 done
        if (it + 1 < nk) {
            const float* rn = rowp + 16 * NUP;
            #pragma unroll
            for (int ch = 0; ch < 3; ++ch)
                __builtin_amdgcn_global_load_lds(
                    (const __attribute__((address_space(1))) void*)(rn + ch * 256 + l * 4),
                    (__attribute__((address_space(3))) void*)&win[(it + 1) & 1][w][ch * 256],
                    16, 0, 0);
        }
        const float* winf = &win[it & 1][0][0];

        if (myint) {
            // ---- interior: symmetric geometry (R10-proven), ds_read2 gathers ---------
            const float4 tv = tvp[0];                     // cb = tv.z, sb = tv.w
            float a = fmaf(tv.z, X, tv.w * Y);            // t0
            float bb = fmaf(tv.z, Y, -tv.w * X);          // s0
            float aK = a * Kc, bK = bb * Kc;
            float D0 = 595.0f - bb, D1 = 595.0f + a, D2 = 595.0f + bb, D3 = 595.0f - a;
            float r0 = __builtin_amdgcn_rcpf(D0);
            float r1 = __builtin_amdgcn_rcpf(D1);
            float r2 = __builtin_amdgcn_rcpf(D2);
            float r3 = __builtin_amdgcn_rcpf(D3);
            float fi0 = fmaf(aK,  r0, 367.5f);
            float fi1 = fmaf(bK,  r1, 367.5f);
            float fi2 = fmaf(-aK, r2, 367.5f);
            float fi3 = fmaf(-bK, r3, 367.5f);
            int im[4] = {(int)fi0, (int)fi1, (int)fi2, (int)fi3};  // in [1,733]
            float ff[4] = {__builtin_amdgcn_fractf(fi0), __builtin_amdgcn_fractf(fi1),
                           __builtin_amdgcn_fractf(fi2), __builtin_amdgcn_fractf(fi3)};
            float gg[4] = {r0 * r0, r1 * r1, r2 * r2, r3 * r3};
            float* accp[4] = {&acc0, &acc1, &acc2, &acc3};
            #pragma unroll
            for (int m = 0; m < 4; ++m) {
                #pragma unroll
                for (int k = 0; k < 4; ++k) {
                    const float* p = winf + (k * NUP + im[m]);
                    float q0 = p[0];                      // ds_read2_b32 (fused pair)
                    float q1 = p[1];
                    float val = fmaf(ff[m], q1 - q0, q0);
                    *accp[(m - k) & 3] = fmaf(gg[m], val, *accp[(m - k) & 3]);
                }
            }
        } else {
            // ---- exterior: R3-exact chains/gates per pixel, staged ds_read2 fetch ----
            const float4 tvs[4] = {tvp[0], tvp[180], tvp[360], tvp[540]};
            const float pX[4] = {X, Y, -X, -Y};
            const float pY[4] = {Y, -X, -Y, X};
            float* accp[4] = {&acc0, &acc1, &acc2, &acc3};
            #pragma unroll
            for (int j = 0; j < 4; ++j) {
                float Xm = pX[j], Ym = pY[j];
                #pragma unroll
                for (int k = 0; k < 4; ++k) {
                    const float4 tv = tvs[k];
                    float t2 = fmaf(tv.x, Xm, tv.y * Ym);               // R3-exact
                    float D  = fmaf(tv.w, Xm, fmaf(tv.z, -Ym, 595.0f)); // R3-exact
                    float rD = __builtin_amdgcn_rcpf(D);
                    float fidx = fmaf(t2, rD, 367.5f);
                    int i0c = min(max((int)fidx, 0), NU - 2);           // v_med3_i32
                    float f = __builtin_amdgcn_fractf(fidx);
                    const float* p = winf + (k * NUP + i0c);
                    float q0 = p[0];                                    // ds_read2_b32
                    float q1 = p[1];
                    float val = fmaf(f, q1 - q0, q0);
                    float cen = fidx - 367.5f;                          // R3-exact gate
                    float g = (__builtin_fabsf(cen) <= 367.5f) ? rD * rD : 0.0f;
                    *accp[j] = fmaf(g, val, *accp[j]);
                }
            }
        }
        rowp += 16 * NUP;
        tvp += 16;
    }
    const float SC = (float)(595.0 * 595.0 * 0.5 * (2.0 * M_PI / 720.0));
    const int ir = 511 - iq, jr = 511 - jq;
    unsafeAtomicAdd(&out[iq * NXY + jq], acc0 * SC);   // P0 = (iq, jq)
    unsafeAtomicAdd(&out[jq * NXY + ir], acc1 * SC);   // P1 = (jq, 511-iq)
    unsafeAtomicAdd(&out[ir * NXY + jr], acc2 * SC);   // P2 = (511-iq, 511-jq)
    unsafeAtomicAdd(&out[jr * NXY + iq], acc3 * SC);   // P3 = (511-jq, iq)
}

extern "C" void kernel_launch(void* const* d_in, const int* in_sizes, int n_in,
                              void* d_out, int out_size, void* d_ws, size_t ws_size,
                              hipStream_t stream) {
    const float* sino = (const float*)d_in[0];
    float* out = (float*)d_out;
    float* Q = (float*)d_ws;                                           // 720*768*4 = 2.21 MB
    float4* trig = (float4*)((char*)d_ws + (size_t)NV * NUP * sizeof(float)); // 16B-aligned

    filter_kernel<<<NV / 4, 192, 0, stream>>>(sino, Q, trig, out);     // also zeroes out
    bp_kernel<<<4096, 256, 0, stream>>>(Q, trig, out);
}